// Round 8
// baseline (308.100 us; speedup 1.0000x reference)
//
#include <hip/hip_runtime.h>

namespace {
constexpr int Bn = 8, Cn = 256, Hn = 64, Wn = 64;
constexpr int Kk = 5, PAD = 2, KMC = 100;   // KMC = UP^2 * K^2
constexpr int SLICES = 8;                   // channel-slice blocks per (b,h)
constexpr int CPB = Cn / SLICES;            // 32 channels per block
constexpr int NCB = CPB / 4;                // 8 channel-group iterations
constexpr int NWG = Hn * Bn * SLICES;       // 4096 single-wave blocks
constexpr int NXCD = 8;
constexpr int CHUNK = NWG / NXCD;           // 512 -> one batch image per XCD
constexpr int HW = Hn * Wn;                 // 4096
}

// Round 8 = round 7 resubmitted (round-7 bench died of container infra,
// no counters). Same body as round 5, __launch_bounds__ (64,2) -> (64,4).
//
// OCCUPANCY-CLASS THEORY (unifies all 7 prior rounds): measured residency
// tracks ONLY the launch-bounds 2nd arg (waves/EU class), never the used
// VGPR count / LDS / grid: (·,2) classes all sat at ~19-21% occupancy,
// (256,4) hit 41%. The runtime reserves the CLASS budget (512/wpe VGPRs
// per wave), so declaring 2 caps us at 2 waves/SIMD even though the body
// uses 112 regs. (64,4) => budget 512/4 = 128 >= 112 -> ZERO spill risk
// (unlike rounds 1-2 where (256,4)'s 64-reg budget spilled wreg[100]),
// cap 16 waves/CU; LDS 11.3 KB allows 14 blocks/CU -> expect ~44%
// occupancy, 2.3x the concurrency to hide the same per-iter latency.
//
// Body (verified absmax 0.0 in rounds 4-6): single-wave blocks, wave-
// private double-buffered LDS staged by async global_load_lds, counted
// s_waitcnt vmcnt (never 0 in steady state), no barriers, XCD-chunked
// swizzle (one batch image per XCD's L2; FETCH 86.8 -> 23.8 MB).
__global__ __launch_bounds__(64, 4) void carafe_fwd(
    const float* __restrict__ x,    // [B, C, H, W]
    const float* __restrict__ km,   // [B, 100, H, W]
    float* __restrict__ out)        // [B, C, 2H, 2W]
{
    // XCD-chunked swizzle: orig = slice + 8*(h + 64*b), CHUNK=512 ->
    // XCD i serves batch image i: its x-panel (4 MB) == its L2 capacity;
    // the 8 slice-blocks of one (b,h) share the km row in L2; h-neighbours
    // share 4/5 x rows.
    const int wg   = blockIdx.x;
    const int orig = (wg & (NXCD - 1)) * CHUNK + (wg >> 3);
    const int sl   = orig & (SLICES - 1);
    const int h    = (orig >> 3) & (Hn - 1);
    const int b    = orig >> 9;

    const int w = threadIdx.x;   // lane 0..63

    // double-buffered wave-private staging: [buf][row][col][ch]
    __shared__ __align__(16) float xs[2][Kk][68][4];
    __shared__ float dummy[64];   // discard target for out-of-range rows

    // zero both buffers once: invalid rows + halo cols stay zero forever
    {
        float* slab = &xs[0][0][0][0];
        for (int i = w; i < 2 * Kk * 68 * 4; i += 64) slab[i] = 0.0f;
    }
    // DS zero-writes must complete before any async VMEM->LDS write lands
    asm volatile("s_waitcnt lgkmcnt(0)" ::: "memory");

    // per-pixel reassembly weights -> 100 registers (reused over 32 ch)
    float wreg[KMC];
    {
        const float* kmp = km + (((size_t)b * KMC) * Hn + h) * Wn + w;
        #pragma unroll
        for (int ch = 0; ch < KMC; ++ch)
            wreg[ch] = kmp[(size_t)ch * HW];
    }

    const float* xb = x + (size_t)b * Cn * HW;
    float* ob       = out + (size_t)b * Cn * (2 * Hn) * (2 * Wn);

    // staging lane split: lane l -> channel (l&3), col (l>>2) of a 16-col
    // chunk; LDS dest = chunk_base + lane*4 in the [col][ch] layout.
    const int sl_ch = w & 3;
    const int sl_cl = w >> 2;

    // Always exactly 20 global_load_lds (uniform vmcnt bookkeeping):
    // out-of-range rows load a clamped address into the dummy slot.
    auto STAGE = [&](int bi, int c0s) {
        #pragma unroll
        for (int r = 0; r < Kk; ++r) {
            const int hr  = h - PAD + r;
            const int hrc = hr < 0 ? 0 : (hr >= Hn ? Hn - 1 : hr);
            const bool valid = (hr == hrc);                 // wave-uniform
            const float* srow =
                xb + (size_t)(c0s + sl_ch) * HW + hrc * Wn + sl_cl;
            #pragma unroll
            for (int q = 0; q < 4; ++q) {
                float* d = valid ? &xs[bi][r][2 + 16 * q][0] : &dummy[0];
                __builtin_amdgcn_global_load_lds(
                    (const __attribute__((address_space(1))) void*)(srow + 16 * q),
                    (__attribute__((address_space(3))) void*)d, 4, 0, 0);
            }
        }
    };

    const int cbase = sl * CPB;
    STAGE(0, cbase);               // prologue: fill buffer 0

    #pragma unroll 1
    for (int cb = 0; cb < NCB; ++cb) {
        const int c0 = cbase + cb * 4;

        if (cb + 1 < NCB)
            STAGE((cb + 1) & 1, c0 + 4);   // async prefetch next group

        // Wait for THIS buffer's 20 loads; newer in-flight VMEM ops:
        //   cb==0      : STAGE_1 (20)                        -> vmcnt(20)
        //   0<cb<NCB-1 : stores_{cb-1} (8) + STAGE_{cb+1}(20) -> vmcnt(28)
        //   cb==NCB-1  : stores_{cb-1} (8)                   -> vmcnt(8)
        if (cb == 0)            asm volatile("s_waitcnt vmcnt(20)" ::: "memory");
        else if (cb + 1 < NCB)  asm volatile("s_waitcnt vmcnt(28)" ::: "memory");
        else                    asm volatile("s_waitcnt vmcnt(8)"  ::: "memory");

        const int bi = cb & 1;
        float acc[4][4] = {};  // [channel k][subpixel u]
        #pragma unroll
        for (int kh = 0; kh < Kk; ++kh) {
            #pragma unroll
            for (int kw = 0; kw < Kk; ++kw) {
                const float4 tap = *(const float4*)(&xs[bi][kh][w + kw][0]);
                const int t = kh * Kk + kw;
                #pragma unroll
                for (int u = 0; u < 4; ++u) {
                    const float wt = wreg[u * 25 + t];
                    acc[0][u] += tap.x * wt;
                    acc[1][u] += tap.y * wt;
                    acc[2][u] += tap.z * wt;
                    acc[3][u] += tap.w * wt;
                }
            }
        }

        // out[b, c0+k, 2h+i, 2w+j]; 8 global_store_dwordx2 per iteration,
        // lane-consecutive -> 512B contiguous per store
        #pragma unroll
        for (int k = 0; k < 4; ++k) {
            #pragma unroll
            for (int i = 0; i < 2; ++i) {
                float2 o2 = make_float2(acc[k][2 * i + 0], acc[k][2 * i + 1]);
                *(float2*)(&ob[((size_t)(c0 + k) * (2 * Hn) + (2 * h + i)) *
                                   (2 * Wn) + 2 * w]) = o2;
            }
        }
    }
}

extern "C" void kernel_launch(void* const* d_in, const int* in_sizes, int n_in,
                              void* d_out, int out_size, void* d_ws, size_t ws_size,
                              hipStream_t stream)
{
    const float* x  = (const float*)d_in[0];
    const float* km = (const float*)d_in[1];
    float* out      = (float*)d_out;

    dim3 grid(NWG);
    carafe_fwd<<<grid, 64, 0, stream>>>(x, km, out);
}

// Round 9
// 197.397 us; speedup vs baseline: 1.5608x; 1.5608x over previous
//
#include <hip/hip_runtime.h>

namespace {
constexpr int Bn = 8, Cn = 256, Hn = 64, Wn = 64;
constexpr int Kk = 5, PAD = 2, KMC = 100, KK2 = 25;  // KMC = UP^2*K^2
constexpr int CSPLIT = 2;                   // channel-split blocks per (b,h)
constexpr int CPB = Cn / CSPLIT;            // 128 channels per block
constexpr int NCB = CPB / 16;               // 8 channel-group iterations
constexpr int NWG = Hn * Bn * CSPLIT;       // 1024 workgroups (4-wave)
constexpr int NXCD = 8;
constexpr int CHUNK = NWG / NXCD;           // 128 consecutive origs per XCD
constexpr int HW = Hn * Wn;                 // 4096
}

// Round 9: the untested quadrant — HIGH OCCUPANCY WITHOUT SPILL.
// Empirical law from rounds 0-8 on this toolchain: VGPR cap = 256/W for
// __launch_bounds__(_,W) (W=2 -> 128, W=4 -> 64), and runtime residency
// follows the W class (W=2 stuck at ~19-21% occupancy in EVERY variant;
// W=4 reached 32-41% but always spilled wreg[100] against the 64 cap).
// VALU-busy TIME is constant ~15us across all non-spill rounds; duration
// = 15us / VALUBusy -> raising occupancy is the only remaining lever.
//
// To fit 64 VGPRs: weights live in block-shared LDS as float4 per
// (tap, lane) -> ONE ds_read_b128 per tap yields all 4 subpixel weights
// (fixes R6's 4x b32 overhead). acc[16] + a few tap/wt pairs + addressing
// ~= 55 regs. xs is wave-private SINGLE-buffered (dropping the double
// buffer pays for kw4's 25.6 KB): LDS = 21.8 + 25.6 = 47.7 KB -> 3
// blocks/CU = 12 waves/CU (37.5%). Async global_load_lds staging kept
// (zero staging VGPRs); single buffer forces vmcnt(0) per iter, covered
// by cross-block overlap at 3 blocks/CU.
__global__ __launch_bounds__(256, 4) void carafe_fwd(
    const float* __restrict__ x,    // [B, C, H, W]
    const float* __restrict__ km,   // [B, 100, H, W]
    float* __restrict__ out)        // [B, C, 2H, 2W]
{
    // XCD-chunked swizzle (kept: FETCH 86.8 -> 23.8 MB)
    const int wg   = blockIdx.x;
    const int orig = (wg & (NXCD - 1)) * CHUNK + (wg >> 3);
    const int cz   = orig & 1;
    const int h    = (orig >> 1) & (Hn - 1);
    const int b    = orig >> 7;

    const int tid = threadIdx.x;
    const int wv  = tid >> 6;
    const int w   = tid & 63;

    // wave-private single-buffer staging tile: [wave][row][col][ch]
    __shared__ __align__(16) float xs[4][Kk][68][4];
    // block-shared weights: kw4[t][w] = {u0,u1,u2,u3} for pixel (h,w)
    __shared__ __align__(16) float4 kw4[KK2][64];
    __shared__ float dummy[64];   // discard target for out-of-range rows

    // zero own slab once: invalid rows + halo cols stay zero forever
    {
        float* slab = &xs[wv][0][0][0];
        for (int i = w; i < Kk * 68 * 4; i += 64) slab[i] = 0.0f;
    }

    // cooperative one-time weight staging with transpose:
    // km[b][u*25+t][h][ww] -> kw4[t][ww][u]. Reads coalesced (256B per
    // 64-lane group); scattered b32 LDS writes are a one-time cost.
    {
        const float* kmb = km + ((size_t)b * KMC) * HW + h * Wn;
        for (int idx = tid; idx < KMC * 64; idx += 256) {
            const int ch = idx >> 6;          // 0..99 = u*25 + t
            const int ww = idx & 63;
            const int u  = ch / KK2;
            const int t  = ch - u * KK2;
            ((float*)&kw4[t][ww])[u] = kmb[(size_t)ch * HW + ww];
        }
    }

    __syncthreads();  // kw4 + xs zeros visible; drains prologue VMEM

    const float* xb = x + (size_t)b * Cn * HW;
    float* ob       = out + (size_t)b * Cn * (2 * Hn) * (2 * Wn);

    // staging lane split: lane l -> channel (l&3), col (l>>2) of a 16-col
    // chunk; LDS dest = chunk_base + lane*4 in the [col][ch] layout.
    const int sl_ch = w & 3;
    const int sl_cl = w >> 2;

    // Exactly 20 global_load_lds per call; out-of-range rows load a
    // clamped address into the dummy slot (uniform vmcnt bookkeeping).
    auto STAGE = [&](int c0s) {
        #pragma unroll
        for (int r = 0; r < Kk; ++r) {
            const int hr  = h - PAD + r;
            const int hrc = hr < 0 ? 0 : (hr >= Hn ? Hn - 1 : hr);
            const bool valid = (hr == hrc);                 // wave-uniform
            const float* srow =
                xb + (size_t)(c0s + sl_ch) * HW + hrc * Wn + sl_cl;
            #pragma unroll
            for (int q = 0; q < 4; ++q) {
                float* d = valid ? &xs[wv][r][2 + 16 * q][0] : &dummy[0];
                __builtin_amdgcn_global_load_lds(
                    (const __attribute__((address_space(1))) void*)(srow + 16 * q),
                    (__attribute__((address_space(3))) void*)d, 4, 0, 0);
            }
        }
    };

    #pragma unroll 1
    for (int cb = 0; cb < NCB; ++cb) {
        const int c0 = cz * CPB + cb * 16 + wv * 4;

        // prior iteration's tap ds_reads must have retired before the DMA
        // can overwrite the (single) buffer
        asm volatile("s_waitcnt lgkmcnt(0)" ::: "memory");
        STAGE(c0);
        // single buffer: must drain this STAGE's 20 loads (in-order vmcnt
        // also drains last iter's 8 stores; acceptable at 3 blocks/CU)
        asm volatile("s_waitcnt vmcnt(0)" ::: "memory");

        float acc[4][4] = {};  // [channel k][subpixel u]
        #pragma unroll
        for (int kh = 0; kh < Kk; ++kh) {
            #pragma unroll
            for (int kwi = 0; kwi < Kk; ++kwi) {
                const int t = kh * Kk + kwi;
                const float4 tap = *(const float4*)(&xs[wv][kh][w + kwi][0]);
                const float4 wt  = kw4[t][w];
                acc[0][0] += tap.x * wt.x; acc[0][1] += tap.x * wt.y;
                acc[0][2] += tap.x * wt.z; acc[0][3] += tap.x * wt.w;
                acc[1][0] += tap.y * wt.x; acc[1][1] += tap.y * wt.y;
                acc[1][2] += tap.y * wt.z; acc[1][3] += tap.y * wt.w;
                acc[2][0] += tap.z * wt.x; acc[2][1] += tap.z * wt.y;
                acc[2][2] += tap.z * wt.z; acc[2][3] += tap.z * wt.w;
                acc[3][0] += tap.w * wt.x; acc[3][1] += tap.w * wt.y;
                acc[3][2] += tap.w * wt.z; acc[3][3] += tap.w * wt.w;
            }
        }

        // out[b, c0+k, 2h+i, 2w+j]; 8 global_store_dwordx2 per iteration,
        // lane-consecutive -> 512B contiguous per store
        #pragma unroll
        for (int k = 0; k < 4; ++k) {
            #pragma unroll
            for (int i = 0; i < 2; ++i) {
                float2 o2 = make_float2(acc[k][2 * i + 0], acc[k][2 * i + 1]);
                *(float2*)(&ob[((size_t)(c0 + k) * (2 * Hn) + (2 * h + i)) *
                                   (2 * Wn) + 2 * w]) = o2;
            }
        }
    }
}

extern "C" void kernel_launch(void* const* d_in, const int* in_sizes, int n_in,
                              void* d_out, int out_size, void* d_ws, size_t ws_size,
                              hipStream_t stream)
{
    const float* x  = (const float*)d_in[0];
    const float* km = (const float*)d_in[1];
    float* out      = (float*)d_out;

    dim3 grid(NWG);
    carafe_fwd<<<grid, 256, 0, stream>>>(x, km, out);
}